// Round 9
// baseline (115.002 us; speedup 1.0000x reference)
//
#include <hip/hip_runtime.h>
#include <math.h>

#define NN 8192
#define DD 64
#define EE 64
#define NB 2
#define THRESH 0.7f
#define JT 64
#define IC 64
#define ISPLIT 8
#define ISPAN (NN / ISPLIT)
#define LOG2E 1.4426950408889634f

typedef __attribute__((ext_vector_type(8))) short bf16x8;
typedef __attribute__((ext_vector_type(4))) float f32x4;
typedef __fp16 half2v __attribute__((ext_vector_type(2)));

static __device__ __forceinline__ short f2bf(float x) {  // RNE
    unsigned u = __float_as_uint(x);
    unsigned r = (u + 0x7fffu + ((u >> 16) & 1u)) >> 16;
    return (short)r;
}
static __device__ __forceinline__ unsigned pack_bf_trunc(float lo, float hi) {
    return __builtin_amdgcn_perm(__float_as_uint(hi), __float_as_uint(lo), 0x07060302u);
}

// ---------------------------------------------------------------------------
// Prep: blocks [0,128): P = U@W via MFMA + U -> bf16.
//       blocks [128,256): es fragment-major transpose + out = S passthrough
//       (es blocks stream all of S anyway; writing out=S here lets the
//       transfer kernel accumulate with fp32 atomics -> no reduce kernel).
// ---------------------------------------------------------------------------
__global__ __launch_bounds__(256) void prep_kernel(const float* __restrict__ U,
                                                   const float* __restrict__ W,
                                                   const float* __restrict__ S,
                                                   const float* __restrict__ prof,
                                                   short* __restrict__ P_bf,
                                                   short* __restrict__ U_bf,
                                                   short* __restrict__ es_f,
                                                   float* __restrict__ out) {
    __shared__ float smem[64 * 132 + 128];  // 34.3 KB (covers both roles)
    const int t = threadIdx.x;
    const f32x4 zero = (f32x4){0.f, 0.f, 0.f, 0.f};

    if (blockIdx.x < 128) {
        // ---- P = U@W with 16x16x32 bf16 MFMA ----
        float* WT = smem;  // [64][68] transposed W (+68 pad: 2-way alias only)
        for (int x = 0; x < 16; ++x) {
            const int idx = x * 256 + t;     // idx = k*64 + f
            const int k = idx >> 6, f = idx & 63;
            WT[f * 68 + k] = W[idx];
        }
        __syncthreads();

        const int w = t >> 6, lane = t & 63, q = lane >> 4, ln = lane & 15;
        const int r0 = blockIdx.x * 64 + w * 16;

        bf16x8 a[2];
#pragma unroll
        for (int ks = 0; ks < 2; ++ks) {
            const float4 u0 = *(const float4*)(U + (r0 + ln) * EE + ks * 32 + q * 8);
            const float4 u1 = *(const float4*)(U + (r0 + ln) * EE + ks * 32 + q * 8 + 4);
            bf16x8 v;
            v[0] = f2bf(u0.x); v[1] = f2bf(u0.y); v[2] = f2bf(u0.z); v[3] = f2bf(u0.w);
            v[4] = f2bf(u1.x); v[5] = f2bf(u1.y); v[6] = f2bf(u1.z); v[7] = f2bf(u1.w);
            a[ks] = v;
            *(bf16x8*)(U_bf + (r0 + ln) * EE + ks * 32 + q * 8) = v;
        }
        bf16x8 b[4][2];
#pragma unroll
        for (int ct = 0; ct < 4; ++ct)
#pragma unroll
            for (int ks = 0; ks < 2; ++ks) {
                const float* wp = WT + (ct * 16 + ln) * 68 + ks * 32 + q * 8;
                const float4 w0 = *(const float4*)wp;
                const float4 w1 = *(const float4*)(wp + 4);
                bf16x8 v;
                v[0] = f2bf(w0.x); v[1] = f2bf(w0.y); v[2] = f2bf(w0.z); v[3] = f2bf(w0.w);
                v[4] = f2bf(w1.x); v[5] = f2bf(w1.y); v[6] = f2bf(w1.z); v[7] = f2bf(w1.w);
                b[ct][ks] = v;
            }
#pragma unroll
        for (int ct = 0; ct < 4; ++ct) {
            f32x4 s = __builtin_amdgcn_mfma_f32_16x16x32_bf16(a[0], b[ct][0], zero, 0, 0, 0);
            s = __builtin_amdgcn_mfma_f32_16x16x32_bf16(a[1], b[ct][1], s, 0, 0, 0);
#pragma unroll
            for (int r = 0; r < 4; ++r)
                P_bf[(r0 + 4 * q + r) * EE + ct * 16 + ln] = f2bf(s[r]);
        }
    } else {
        float* tr = smem;           // [64][132]
        float* gl = smem + 8448;    // [128]
        const int bi = blockIdx.x - 128;  // 0..127
        const int b = bi >> 6;
        const int i0 = (bi & 63) * 128;
        if (t < 128) gl[t] = fmaxf(prof[b * NN + i0 + t] - THRESH, 0.f);
        __syncthreads();
#pragma unroll
        for (int k = 0; k < 8; ++k) {
            const int idx = k * 256 + t;  // 2048 = 128 i x 16 c4
            const int i = idx >> 4, c4 = idx & 15;
            const float g = gl[i];
            const float4 s = ((const float4*)S)[(b * NN + i0 + i) * 16 + c4];
            ((float4*)out)[(b * NN + i0 + i) * 16 + c4] = s;  // out = S
            tr[(c4 * 4 + 0) * 132 + i] = s.x * g;
            tr[(c4 * 4 + 1) * 132 + i] = s.y * g;
            tr[(c4 * 4 + 2) * 132 + i] = s.z * g;
            tr[(c4 * 4 + 3) * 132 + i] = s.w * g;
        }
        __syncthreads();
#pragma unroll
        for (int pass = 0; pass < 4; ++pass) {
            const int d = pass * 16 + (t >> 4);   // within-b row 0..63
            const int i8 = t & 15;                // 8-element i-group 0..15
            const float4 a = *(const float4*)&tr[d * 132 + i8 * 8];
            const float4 c = *(const float4*)&tr[d * 132 + i8 * 8 + 4];
            bf16x8 v;
            v[0] = f2bf(a.x); v[1] = f2bf(a.y); v[2] = f2bf(a.z); v[3] = f2bf(a.w);
            v[4] = f2bf(c.x); v[5] = f2bf(c.y); v[6] = f2bf(c.z); v[7] = f2bf(c.w);
            // fragment-major address
            const int cg = (bi & 63) * 2 + (i8 >> 3);  // 64-i chunk
            const int ks = (i8 >> 2) & 1;
            const int q  = i8 & 3;
            const int g  = b * 4 + (d >> 4);
            const int lane = q * 16 + (d & 15);
            *(bf16x8*)(es_f + ((((cg * 8 + g) * 2 + ks) << 9) + lane * 8)) = v;
        }
    }
}

// ---------------------------------------------------------------------------
// Transfer: R7 structure (verified); epilogue now fp32 atomicAdd directly
// into out (pre-initialized to S by prep) -> reduce kernel eliminated.
// ---------------------------------------------------------------------------
__global__ __launch_bounds__(256, 3) void transfer_kernel(const short* __restrict__ P_bf,
                                                          const short* __restrict__ U_bf,
                                                          const short* __restrict__ es_f,
                                                          const float* __restrict__ bias_p,
                                                          float* __restrict__ out) {
    // T in MFMA-A fragment order, double-buffered: [buf][tile][lane][8 shorts]
    __shared__ __align__(16) short TT[2][8 * 64 * 8];  // 16 KB

    const int t = threadIdx.x;
    const int w = t >> 6;
    const int lane = t & 63;
    const int q = lane >> 4;
    const int ln = lane & 15;
    const int j0 = blockIdx.x * JT;
    const int i_base = blockIdx.y * ISPAN;
    const int cg_base = blockIdx.y * (ISPAN / 64);
    const float nb = -bias_p[0] * LOG2E;

    // U B-fragments resident for the whole kernel
    bf16x8 uf[4][2];
#pragma unroll
    for (int jt = 0; jt < 4; ++jt)
#pragma unroll
        for (int ks = 0; ks < 2; ++ks)
            uf[jt][ks] = *(const bf16x8*)(U_bf + (j0 + jt * 16 + ln) * EE + ks * 32 + q * 8);

    f32x4 acc[4][2];
#pragma unroll
    for (int jm = 0; jm < 4; ++jm)
#pragma unroll
        for (int c = 0; c < 2; ++c) acc[jm][c] = (f32x4){0.f, 0.f, 0.f, 0.f};
    const f32x4 zero = (f32x4){0.f, 0.f, 0.f, 0.f};

    // producer TT slot: i_local=16w+4q+r -> ks=(w>>1), q'=(2w+(q>>1))&3, half=(q&1)
    const int ks_w = w >> 1;
    const int qp = (2 * w + (q >> 1)) & 3;
    const int ttw_off = (ks_w * 64 + qp * 16 + ln) * 2 + (q & 1);  // uint2 units

    auto load_p = [&](int cc, bf16x8* pf) {
        const int i0 = i_base + cc * IC;
#pragma unroll
        for (int ks = 0; ks < 2; ++ks)
            pf[ks] = *(const bf16x8*)(P_bf + (i0 + w * 16 + ln) * EE + ks * 32 + q * 8);
    };
    auto load_es = [&](int cc, bf16x8 (*bfr)[2]) {
        const int cg = cg_base + cc;
#pragma unroll
        for (int c = 0; c < 2; ++c) {
            const int g = w * 2 + c;
            const short* er = es_f + (((cg * 8 + g) * 2) << 9) + lane * 8;
#pragma unroll
            for (int ks = 0; ks < 2; ++ks)
                bfr[c][ks] = *(const bf16x8*)(er + (ks << 9));
        }
    };
    auto phase_a = [&](int cc, const bf16x8* pf, short* tt) {
        const int i0 = i_base + cc * IC;
        const bool dg = (i0 == j0);
#pragma unroll
        for (int jt = 0; jt < 4; ++jt) {
            f32x4 s = __builtin_amdgcn_mfma_f32_16x16x32_bf16(pf[0], uf[jt][0], zero, 0, 0, 0);
            s = __builtin_amdgcn_mfma_f32_16x16x32_bf16(pf[1], uf[jt][1], s, 0, 0, 0);
            float T[4];
#pragma unroll
            for (int r = 0; r < 4; ++r)
                T[r] = __builtin_amdgcn_rcpf(
                    1.f + __builtin_amdgcn_exp2f(fmaf(s[r], -LOG2E, nb)));
            if (dg && jt == w) {  // diagonal 16x16 sub-tile
                const int rr = ln - 4 * q;
                if (rr >= 0 && rr < 4) T[rr] = 0.f;
            }
            uint2 pk;
            pk.x = pack_bf_trunc(T[0], T[1]);
            pk.y = pack_bf_trunc(T[2], T[3]);
            ((uint2*)tt)[jt * 256 + ttw_off] = pk;
        }
    };
    auto phase_b = [&](const bf16x8 (*bfr)[2], const short* tt) {
#pragma unroll
        for (int jm = 0; jm < 4; ++jm)
#pragma unroll
            for (int ks = 0; ks < 2; ++ks) {
                const bf16x8 af = *(const bf16x8*)(tt + ((jm * 2 + ks) * 64 + lane) * 8);
                acc[jm][0] = __builtin_amdgcn_mfma_f32_16x16x32_bf16(af, bfr[0][ks], acc[jm][0], 0, 0, 0);
                acc[jm][1] = __builtin_amdgcn_mfma_f32_16x16x32_bf16(af, bfr[1][ks], acc[jm][1], 0, 0, 0);
            }
    };

    // prologue
    bf16x8 pfA[2], pfB[2], bfA[2][2], bfB[2][2];
    load_p(0, pfA);
    load_es(0, bfA);
    load_p(1, pfB);
    phase_a(0, pfA, TT[0]);
    __syncthreads();  // TT[0] ready

    const int NCH = ISPAN / IC;  // 16
#pragma unroll
    for (int c = 0; c < NCH; c += 2) {
        // even iter: A(c+1)->TT1 || B(c)<-TT0
        if (c + 1 < NCH) load_es(c + 1, bfB);
        if (c + 2 < NCH) load_p(c + 2, pfA);
        if (c + 1 < NCH) phase_a(c + 1, pfB, TT[1]);
        phase_b(bfA, TT[0]);
        __syncthreads();
        // odd iter: A(c+2)->TT0 || B(c+1)<-TT1
        if (c + 2 < NCH) load_es(c + 2, bfA);
        if (c + 3 < NCH) load_p(c + 3, pfB);
        if (c + 2 < NCH) phase_a(c + 2, pfA, TT[0]);
        if (c + 1 < NCH) phase_b(bfB, TT[1]);
        __syncthreads();
    }

    // epilogue: fp32 atomic accumulate into out (= S + sum over y-blocks)
#pragma unroll
    for (int jm = 0; jm < 4; ++jm)
#pragma unroll
        for (int c = 0; c < 2; ++c) {
            const int g = w * 2 + c;
            const int bb = g >> 2, dt = g & 3;
            const int j = j0 + jm * 16 + q * 4;
            float* op = out + (size_t)(bb * NN + j) * DD + dt * 16 + ln;
#pragma unroll
            for (int r = 0; r < 4; ++r)
                atomicAdd(op + r * DD, acc[jm][c][r]);
        }
}

// ---------------------------------------------------------------------------
extern "C" void kernel_launch(void* const* d_in, const int* in_sizes, int n_in,
                              void* d_out, int out_size, void* d_ws, size_t ws_size,
                              hipStream_t stream) {
    const float* states = (const float*)d_in[0];  // [B,N,D]
    const float* prof   = (const float*)d_in[1];  // [B,N]
    const float* emb    = (const float*)d_in[2];  // [N,E]
    const float* W      = (const float*)d_in[3];  // [1,E,E]
    const float* bias   = (const float*)d_in[4];  // [1]
    float* out = (float*)d_out;

    short* P_bf = (short*)d_ws;                 // 1 MB
    short* U_bf = P_bf + NN * EE;               // 1 MB
    short* es_f = U_bf + NN * EE;               // 2 MB (fragment-major tiles)

    prep_kernel<<<256, 256, 0, stream>>>(emb, W, states, prof, P_bf, U_bf, es_f, out);
    transfer_kernel<<<dim3(NN / JT, ISPLIT), 256, 0, stream>>>(P_bf, U_bf, es_f, bias, out);
}